// Round 1
// baseline (999.559 us; speedup 1.0000x reference)
//
#include <hip/hip_runtime.h>

// Problem constants
#define BB 4
#define SS 1024
#define DD 512
#define HH 16
#define DH 32

// ws layout (in floats)
#define OFF_Q   0u
#define OFF_K   2097152u
#define OFF_V   4194304u
#define OFF_P   6291456u
#define OFF_CTX 6815744u
#define OFF_MASK 8912896u   // int region, 4096 ints

// ---------------------------------------------------------------------------
// Mask normalization: detect byte-bool vs int32 layout, expand to int[4096].
// ---------------------------------------------------------------------------
__global__ void mask_prep_kernel(const unsigned char* __restrict__ raw,
                                 int* __restrict__ norm) {
    __shared__ int bad;
    if (threadIdx.x == 0) bad = 0;
    __syncthreads();
    // First 4096 bytes are in-bounds under both layouts.
    const unsigned int* w = (const unsigned int*)raw;
    int isbad = 0;
    for (int i = threadIdx.x; i < 1024; i += 256)
        if (w[i] > 1u) isbad = 1;
    if (isbad) atomicOr(&bad, 1);
    __syncthreads();
    if (bad) {  // byte/bool layout
        for (int i = threadIdx.x; i < BB * SS; i += 256)
            norm[i] = raw[i] != 0;
    } else {    // int32 layout
        const int* wi = (const int*)raw;
        for (int i = threadIdx.x; i < BB * SS; i += 256)
            norm[i] = wi[i] != 0;
    }
}

// ---------------------------------------------------------------------------
// Generic fp32 GEMM:  C[M x 512] = A[M x 512] @ W[512 x 512] (+ bias)
// 64x64 block tile, 256 threads, 4x4 per thread, BK=16. No LDS transpose.
// ---------------------------------------------------------------------------
__global__ __launch_bounds__(256) void gemm_bias_kernel(
    const float* __restrict__ A, const float* __restrict__ W,
    const float* __restrict__ bias, float* __restrict__ C) {
    __shared__ float As[64][20];   // row-major, stride 20 floats (80B, 16B-aligned)
    __shared__ float Ws[16][72];   // stride 72 floats (288B, 16B-aligned)
    const int tid = threadIdx.x;
    const int tx = tid & 15, ty = tid >> 4;
    const int m0 = blockIdx.x * 64, n0 = blockIdx.y * 64;
    const int lr = tid >> 2;            // 0..63 (A row)
    const int lk4 = (tid & 3) * 4;      // 0,4,8,12 (A k)
    const int wk = tid >> 4;            // 0..15 (W k)
    const int wn4 = (tid & 15) * 4;     // W n
    float acc[4][4] = {};
    for (int k0 = 0; k0 < 512; k0 += 16) {
        __syncthreads();
        *(float4*)&As[lr][lk4] =
            *(const float4*)(A + (size_t)(m0 + lr) * 512 + k0 + lk4);
        *(float4*)&Ws[wk][wn4] =
            *(const float4*)(W + (size_t)(k0 + wk) * 512 + n0 + wn4);
        __syncthreads();
#pragma unroll
        for (int kk4 = 0; kk4 < 16; kk4 += 4) {
            float4 w0 = *(const float4*)&Ws[kk4 + 0][tx * 4];
            float4 w1 = *(const float4*)&Ws[kk4 + 1][tx * 4];
            float4 w2 = *(const float4*)&Ws[kk4 + 2][tx * 4];
            float4 w3 = *(const float4*)&Ws[kk4 + 3][tx * 4];
#pragma unroll
            for (int i = 0; i < 4; ++i) {
                float4 a4 = *(const float4*)&As[ty * 4 + i][kk4];
                acc[i][0] += a4.x * w0.x + a4.y * w1.x + a4.z * w2.x + a4.w * w3.x;
                acc[i][1] += a4.x * w0.y + a4.y * w1.y + a4.z * w2.y + a4.w * w3.y;
                acc[i][2] += a4.x * w0.z + a4.y * w1.z + a4.z * w2.z + a4.w * w3.z;
                acc[i][3] += a4.x * w0.w + a4.y * w1.w + a4.z * w2.w + a4.w * w3.w;
            }
        }
    }
    float4 bv = make_float4(0.f, 0.f, 0.f, 0.f);
    if (bias) bv = *(const float4*)(bias + n0 + tx * 4);
#pragma unroll
    for (int i = 0; i < 4; ++i) {
        float4 o;
        o.x = acc[i][0] + bv.x; o.y = acc[i][1] + bv.y;
        o.z = acc[i][2] + bv.z; o.w = acc[i][3] + bv.w;
        *(float4*)(C + (size_t)(m0 + ty * 4 + i) * 512 + n0 + tx * 4) = o;
    }
}

// ---------------------------------------------------------------------------
// content[b,h,q,k] = (q_row + u_bias) . k_row   -> raw score buffer
// Block: (b,h, 16 q-rows). Each thread keeps 2 q-rows in registers.
// ---------------------------------------------------------------------------
__global__ __launch_bounds__(256) void content_kernel(
    const float* __restrict__ qp, const float* __restrict__ kp,
    const float* __restrict__ ub, float* __restrict__ attn) {
    const int b = blockIdx.z, h = blockIdx.y, q0 = blockIdx.x * 16;
    __shared__ float qs[16][33];
    __shared__ float kt[128][33];
    const int tid = threadIdx.x;
    if (tid < 128) {
        int r = tid / 8, c4 = (tid % 8) * 4;
        float4 qv = *(const float4*)(qp + ((size_t)(b * SS + q0 + r)) * 512 + h * 32 + c4);
        float4 uv = *(const float4*)(ub + h * 32 + c4);
        qs[r][c4 + 0] = qv.x + uv.x; qs[r][c4 + 1] = qv.y + uv.y;
        qs[r][c4 + 2] = qv.z + uv.z; qs[r][c4 + 3] = qv.w + uv.w;
    }
    __syncthreads();
    const int kx = tid & 31, qy = tid >> 5;   // qy 0..7
    float q1[32], q2[32];
#pragma unroll
    for (int d = 0; d < 32; ++d) { q1[d] = qs[qy][d]; q2[d] = qs[qy + 8][d]; }
    float* ob = attn + (((size_t)(b * HH + h)) << 20) + (size_t)q0 * SS;
    const int r = tid / 8, c4 = (tid % 8) * 4;
    for (int kt0 = 0; kt0 < SS; kt0 += 128) {
        __syncthreads();
#pragma unroll
        for (int it = 0; it < 4; ++it) {
            int rr = r + it * 32;
            float4 kv = *(const float4*)(kp + ((size_t)(b * SS + kt0 + rr)) * 512 + h * 32 + c4);
            kt[rr][c4 + 0] = kv.x; kt[rr][c4 + 1] = kv.y;
            kt[rr][c4 + 2] = kv.z; kt[rr][c4 + 3] = kv.w;
        }
        __syncthreads();
#pragma unroll
        for (int ki = 0; ki < 4; ++ki) {
            int kl = kx + ki * 32;
            float s1 = 0.f, s2 = 0.f;
#pragma unroll
            for (int d = 0; d < 32; ++d) {
                float kv = kt[kl][d];
                s1 += q1[d] * kv; s2 += q2[d] * kv;
            }
            ob[(size_t)qy * SS + kt0 + kl] = s1;
            ob[(size_t)(qy + 8) * SS + kt0 + kl] = s2;
        }
    }
}

// ---------------------------------------------------------------------------
// pos[q,j] = (q_row + v_bias) . p_j, scatter-added at the rel-shifted target:
//   j >= S-1-q  ->  (q,   q+j-S+1)
//   else        ->  (q-1, q+j+1)      (dropped if q==0)
// Each source maps to a unique target; targets disjoint across blocks -> no races.
// ---------------------------------------------------------------------------
__global__ __launch_bounds__(256) void pos_kernel(
    const float* __restrict__ qp, const float* __restrict__ pp,
    const float* __restrict__ vb, float* __restrict__ attn) {
    const int b = blockIdx.z, h = blockIdx.y, q0 = blockIdx.x * 16;
    __shared__ float qs[16][33];
    __shared__ float pt[128][33];
    const int tid = threadIdx.x;
    if (tid < 128) {
        int r = tid / 8, c4 = (tid % 8) * 4;
        float4 qv = *(const float4*)(qp + ((size_t)(b * SS + q0 + r)) * 512 + h * 32 + c4);
        float4 vv = *(const float4*)(vb + h * 32 + c4);
        qs[r][c4 + 0] = qv.x + vv.x; qs[r][c4 + 1] = qv.y + vv.y;
        qs[r][c4 + 2] = qv.z + vv.z; qs[r][c4 + 3] = qv.w + vv.w;
    }
    __syncthreads();
    const int kx = tid & 31, qy = tid >> 5;
    float q1[32], q2[32];
#pragma unroll
    for (int d = 0; d < 32; ++d) { q1[d] = qs[qy][d]; q2[d] = qs[qy + 8][d]; }
    float* ab = attn + (((size_t)(b * HH + h)) << 20);
    const int qg1 = q0 + qy, qg2 = q0 + qy + 8;
    const int r = tid / 8, c4 = (tid % 8) * 4;
    for (int j0 = 0; j0 < SS; j0 += 128) {
        __syncthreads();
#pragma unroll
        for (int it = 0; it < 4; ++it) {
            int rr = r + it * 32;
            float4 pv = *(const float4*)(pp + ((size_t)(j0 + rr)) * 512 + h * 32 + c4);
            pt[rr][c4 + 0] = pv.x; pt[rr][c4 + 1] = pv.y;
            pt[rr][c4 + 2] = pv.z; pt[rr][c4 + 3] = pv.w;
        }
        __syncthreads();
#pragma unroll
        for (int ki = 0; ki < 4; ++ki) {
            int jl = kx + ki * 32;
            int j = j0 + jl;
            float s1 = 0.f, s2 = 0.f;
#pragma unroll
            for (int d = 0; d < 32; ++d) {
                float pv = pt[jl][d];
                s1 += q1[d] * pv; s2 += q2[d] * pv;
            }
            // route s1 (source row qg1)
            {
                int tq, tk;
                if (j >= SS - 1 - qg1) { tq = qg1;     tk = qg1 + j - (SS - 1); }
                else                   { tq = qg1 - 1; tk = qg1 + j + 1; }
                if (tq >= 0) ab[(size_t)tq * SS + tk] += s1;
            }
            // route s2 (source row qg2)
            {
                int tq, tk;
                if (j >= SS - 1 - qg2) { tq = qg2;     tk = qg2 + j - (SS - 1); }
                else                   { tq = qg2 - 1; tk = qg2 + j + 1; }
                if (tq >= 0) ab[(size_t)tq * SS + tk] += s2;
            }
        }
    }
}

// ---------------------------------------------------------------------------
// Softmax over each score row: scale, key-mask -> -1e9, exp-normalize.
// One block (256 thr) per row of 1024.
// ---------------------------------------------------------------------------
__global__ __launch_bounds__(256) void softmax_kernel(
    float* __restrict__ attn, const int* __restrict__ mask) {
    const size_t row = blockIdx.x;          // (b*16+h)*1024 + q
    const int b = (int)(row >> 14);
    float* a = attn + (row << 10);
    const int* mrow = mask + ((size_t)b << 10);
    const int tid = threadIdx.x;
    const float scale = 0.04419417382415922f;   // 1/sqrt(512)
    float4 v = *(const float4*)(a + tid * 4);
    int4 mm = *(const int4*)(mrow + tid * 4);
    float s[4];
    s[0] = mm.x ? -1e9f : v.x * scale;
    s[1] = mm.y ? -1e9f : v.y * scale;
    s[2] = mm.z ? -1e9f : v.z * scale;
    s[3] = mm.w ? -1e9f : v.w * scale;
    float m = fmaxf(fmaxf(s[0], s[1]), fmaxf(s[2], s[3]));
#pragma unroll
    for (int off = 32; off >= 1; off >>= 1) m = fmaxf(m, __shfl_xor(m, off, 64));
    __shared__ float redm[4];
    __shared__ float redl[4];
    const int wid = tid >> 6, lane = tid & 63;
    if (lane == 0) redm[wid] = m;
    __syncthreads();
    m = fmaxf(fmaxf(redm[0], redm[1]), fmaxf(redm[2], redm[3]));
    float e[4];
    float l = 0.f;
#pragma unroll
    for (int jj = 0; jj < 4; ++jj) { e[jj] = __expf(s[jj] - m); l += e[jj]; }
#pragma unroll
    for (int off = 32; off >= 1; off >>= 1) l += __shfl_xor(l, off, 64);
    if (lane == 0) redl[wid] = l;
    __syncthreads();
    l = redl[0] + redl[1] + redl[2] + redl[3];
    const float inv = 1.f / l;
    float4 o;
    o.x = e[0] * inv; o.y = e[1] * inv; o.z = e[2] * inv; o.w = e[3] * inv;
    *(float4*)(a + tid * 4) = o;
}

// ---------------------------------------------------------------------------
// ctx[b,q,h,:] = sum_k attn[b,h,q,k] * v[b,k,h,:]
// Block: (b,h, 128 q-rows). 4 rows x 4 cols per thread, BK=64.
// ---------------------------------------------------------------------------
__global__ __launch_bounds__(256) void ctx_kernel(
    const float* __restrict__ attn, const float* __restrict__ vp,
    float* __restrict__ ctx) {
    const int b = blockIdx.z, h = blockIdx.y, q0 = blockIdx.x * 128;
    __shared__ float at[128][68];   // stride 272B, 16B-aligned
    __shared__ float vt[64][40];    // stride 160B, 16B-aligned
    const int tid = threadIdx.x;
    const float* abase = attn + (((size_t)(b * HH + h)) << 20);
    float acc[4][4] = {};
    const int rt = (tid / 8) * 4;     // row base 0..124
    const int cc = (tid % 8) * 4;     // col base 0..28
    const int ar = tid / 16, ac4 = (tid % 16) * 4;  // at loader
    const int vr = tid / 8,  vc4 = (tid % 8) * 4;   // vt loader
    for (int k0 = 0; k0 < SS; k0 += 64) {
        __syncthreads();
#pragma unroll
        for (int it = 0; it < 8; ++it) {
            int rr = ar + it * 16;
            *(float4*)&at[rr][ac4] =
                *(const float4*)(abase + (size_t)(q0 + rr) * SS + k0 + ac4);
        }
#pragma unroll
        for (int it = 0; it < 2; ++it) {
            int rr = vr + it * 32;
            float4 vv = *(const float4*)(vp + ((size_t)(b * SS + k0 + rr)) * 512 + h * 32 + vc4);
            vt[rr][vc4 + 0] = vv.x; vt[rr][vc4 + 1] = vv.y;
            vt[rr][vc4 + 2] = vv.z; vt[rr][vc4 + 3] = vv.w;
        }
        __syncthreads();
#pragma unroll
        for (int kk4 = 0; kk4 < 64; kk4 += 4) {
            float am[4][4];
#pragma unroll
            for (int i = 0; i < 4; ++i) {
                float4 a4 = *(const float4*)&at[rt + i][kk4];
                am[i][0] = a4.x; am[i][1] = a4.y; am[i][2] = a4.z; am[i][3] = a4.w;
            }
#pragma unroll
            for (int jj = 0; jj < 4; ++jj) {
                float4 v4 = *(const float4*)&vt[kk4 + jj][cc];
#pragma unroll
                for (int i = 0; i < 4; ++i) {
                    acc[i][0] += am[i][jj] * v4.x;
                    acc[i][1] += am[i][jj] * v4.y;
                    acc[i][2] += am[i][jj] * v4.z;
                    acc[i][3] += am[i][jj] * v4.w;
                }
            }
        }
    }
#pragma unroll
    for (int i = 0; i < 4; ++i) {
        float4 o;
        o.x = acc[i][0]; o.y = acc[i][1]; o.z = acc[i][2]; o.w = acc[i][3];
        *(float4*)(ctx + ((size_t)(b * SS + q0 + rt + i)) * 512 + h * 32 + cc) = o;
    }
}

// ---------------------------------------------------------------------------
extern "C" void kernel_launch(void* const* d_in, const int* in_sizes, int n_in,
                              void* d_out, int out_size, void* d_ws, size_t ws_size,
                              hipStream_t stream) {
    const float* query = (const float*)d_in[0];
    const float* key   = (const float*)d_in[1];
    const float* value = (const float*)d_in[2];
    const unsigned char* mask_raw = (const unsigned char*)d_in[3];
    const float* enc   = (const float*)d_in[4];
    const float* Wq    = (const float*)d_in[5];
    const float* bq    = (const float*)d_in[6];
    const float* Wk    = (const float*)d_in[7];
    const float* Wv    = (const float*)d_in[8];
    const float* Wp    = (const float*)d_in[9];
    const float* u_b   = (const float*)d_in[10];
    const float* v_b   = (const float*)d_in[11];
    const float* Wo    = (const float*)d_in[12];
    const float* bo    = (const float*)d_in[13];

    float* ws   = (float*)d_ws;
    float* qprj = ws + OFF_Q;
    float* kprj = ws + OFF_K;
    float* vprj = ws + OFF_V;
    float* pprj = ws + OFF_P;
    float* ctx  = ws + OFF_CTX;
    int*   mnrm = (int*)(ws + OFF_MASK);

    float* outp = (float*)d_out;                 // (B,S,D) = 2097152 floats
    float* attn = outp + (size_t)BB * SS * DD;   // (B,H,S,S) = 16777216 floats

    mask_prep_kernel<<<1, 256, 0, stream>>>(mask_raw, mnrm);

    gemm_bias_kernel<<<dim3(64, 8), 256, 0, stream>>>(query, Wq, bq, qprj);
    gemm_bias_kernel<<<dim3(64, 8), 256, 0, stream>>>(key, Wk, nullptr, kprj);
    gemm_bias_kernel<<<dim3(64, 8), 256, 0, stream>>>(value, Wv, nullptr, vprj);
    gemm_bias_kernel<<<dim3(16, 8), 256, 0, stream>>>(enc, Wp, nullptr, pprj);

    content_kernel<<<dim3(SS / 16, HH, BB), 256, 0, stream>>>(qprj, kprj, u_b, attn);
    pos_kernel<<<dim3(SS / 16, HH, BB), 256, 0, stream>>>(qprj, pprj, v_b, attn);
    softmax_kernel<<<BB * HH * SS, 256, 0, stream>>>(attn, mnrm);
    ctx_kernel<<<dim3(SS / 128, HH, BB), 256, 0, stream>>>(attn, vprj, ctx);

    gemm_bias_kernel<<<dim3(64, 8), 256, 0, stream>>>(ctx, Wo, bo, outp);
}

// Round 2
// 828.154 us; speedup vs baseline: 1.2070x; 1.2070x over previous
//
#include <hip/hip_runtime.h>

// Problem constants
#define BB 4
#define SS 1024
#define DD 512
#define HH 16
#define DH 32

// ws layout (in floats)
#define OFF_Q   0u
#define OFF_K   2097152u
#define OFF_V   4194304u
#define OFF_P   6291456u
#define OFF_CTX 6815744u
#define OFF_MASK 8912896u   // int region, 4096 ints

typedef __attribute__((ext_vector_type(8))) short bf16x8;
typedef __attribute__((ext_vector_type(4))) float f32x4;

__device__ __forceinline__ short f2bf(float x) {
    union { float f; unsigned u; } v; v.f = x;
    unsigned r = (v.u + 0x7FFFu + ((v.u >> 16) & 1u)) >> 16;
    return (short)r;
}

// ---------------------------------------------------------------------------
// Mask normalization: detect byte-bool vs int32 layout, expand to int[4096].
// ---------------------------------------------------------------------------
__global__ void mask_prep_kernel(const unsigned char* __restrict__ raw,
                                 int* __restrict__ norm) {
    __shared__ int bad;
    if (threadIdx.x == 0) bad = 0;
    __syncthreads();
    const unsigned int* w = (const unsigned int*)raw;
    int isbad = 0;
    for (int i = threadIdx.x; i < 1024; i += 256)
        if (w[i] > 1u) isbad = 1;
    if (isbad) atomicOr(&bad, 1);
    __syncthreads();
    if (bad) {  // byte/bool layout
        for (int i = threadIdx.x; i < BB * SS; i += 256)
            norm[i] = raw[i] != 0;
    } else {    // int32 layout
        const int* wi = (const int*)raw;
        for (int i = threadIdx.x; i < BB * SS; i += 256)
            norm[i] = wi[i] != 0;
    }
}

// ---------------------------------------------------------------------------
// Generic fp32 GEMM:  C[M x 512] = A[M x 512] @ W[512 x 512] (+ bias)
// (kept fp32 this round to protect the 4.2e-3 output threshold)
// ---------------------------------------------------------------------------
__global__ __launch_bounds__(256) void gemm_bias_kernel(
    const float* __restrict__ A, const float* __restrict__ W,
    const float* __restrict__ bias, float* __restrict__ C) {
    __shared__ float As[64][20];
    __shared__ float Ws[16][72];
    const int tid = threadIdx.x;
    const int tx = tid & 15, ty = tid >> 4;
    const int m0 = blockIdx.x * 64, n0 = blockIdx.y * 64;
    const int lr = tid >> 2;
    const int lk4 = (tid & 3) * 4;
    const int wk = tid >> 4;
    const int wn4 = (tid & 15) * 4;
    float acc[4][4] = {};
    for (int k0 = 0; k0 < 512; k0 += 16) {
        __syncthreads();
        *(float4*)&As[lr][lk4] =
            *(const float4*)(A + (size_t)(m0 + lr) * 512 + k0 + lk4);
        *(float4*)&Ws[wk][wn4] =
            *(const float4*)(W + (size_t)(k0 + wk) * 512 + n0 + wn4);
        __syncthreads();
#pragma unroll
        for (int kk4 = 0; kk4 < 16; kk4 += 4) {
            float4 w0 = *(const float4*)&Ws[kk4 + 0][tx * 4];
            float4 w1 = *(const float4*)&Ws[kk4 + 1][tx * 4];
            float4 w2 = *(const float4*)&Ws[kk4 + 2][tx * 4];
            float4 w3 = *(const float4*)&Ws[kk4 + 3][tx * 4];
#pragma unroll
            for (int i = 0; i < 4; ++i) {
                float4 a4 = *(const float4*)&As[ty * 4 + i][kk4];
                acc[i][0] += a4.x * w0.x + a4.y * w1.x + a4.z * w2.x + a4.w * w3.x;
                acc[i][1] += a4.x * w0.y + a4.y * w1.y + a4.z * w2.y + a4.w * w3.y;
                acc[i][2] += a4.x * w0.z + a4.y * w1.z + a4.z * w2.z + a4.w * w3.z;
                acc[i][3] += a4.x * w0.w + a4.y * w1.w + a4.z * w2.w + a4.w * w3.w;
            }
        }
    }
    float4 bv = make_float4(0.f, 0.f, 0.f, 0.f);
    if (bias) bv = *(const float4*)(bias + n0 + tx * 4);
#pragma unroll
    for (int i = 0; i < 4; ++i) {
        float4 o;
        o.x = acc[i][0] + bv.x; o.y = acc[i][1] + bv.y;
        o.z = acc[i][2] + bv.z; o.w = acc[i][3] + bv.w;
        *(float4*)(C + (size_t)(m0 + ty * 4 + i) * 512 + n0 + tx * 4) = o;
    }
}

// ---------------------------------------------------------------------------
// Fused score kernel (MFMA bf16): raw_score[b,h,q,k] =
//     (q+u).K_k  +  rel_shift((q+v).P)[q,k]
// rel-shift inverse: shifted[q,k] = pos_src[q, k-q+S-1]   (k <= q)
//                                   pos_src[q+1, k-q-2]   (k >= q+2), 0 at k=q+1
// Both cases read local index kk-qq+15 of a 79-wide j-window; out-of-range j
// rows are zero (this also zeroes the k=q+1 term). Block = (b,h,16 q-rows),
// 4 waves x 256 k each, chunks of 64 k. Everything intra-wave (no barrier).
// ---------------------------------------------------------------------------
__global__ __launch_bounds__(256) void score_kernel(
    const float* __restrict__ qp, const float* __restrict__ kp,
    const float* __restrict__ pp, const float* __restrict__ ub,
    const float* __restrict__ vb, float* __restrict__ attn) {
    const int b = blockIdx.z, h = blockIdx.y, q0 = blockIdx.x * 16;
    const int tid = threadIdx.x;
    const int wave = tid >> 6, lane = tid & 63;
    const int ln = lane & 15, quad = lane >> 4;
    __shared__ float posbuf[4][2][16][84];

    // A fragments: lane holds row (ln), d = quad*8 + j  (16x32 tile)
    bf16x8 a_c, a_pA, a_pB;
    {
        const float* qrow = qp + ((size_t)(b * SS + q0 + ln)) * DD + h * DH + quad * 8;
        const int qrB = q0 + ln + 1;   // shifted rows for case-B pos
        const float* qrowB = qp + ((size_t)(b * SS + qrB)) * DD + h * DH + quad * 8;
#pragma unroll
        for (int j = 0; j < 8; ++j) {
            float u = ub[h * DH + quad * 8 + j];
            float v = vb[h * DH + quad * 8 + j];
            float qv = qrow[j];
            a_c[j] = f2bf(qv + u);
            a_pA[j] = f2bf(qv + v);
            a_pB[j] = (qrB < SS) ? f2bf(qrowB[j] + v) : (short)0;
        }
    }

    float* ob = attn + (((size_t)(b * HH + h)) << 20) + (size_t)q0 * SS;
    const float* pbase = pp + h * DH + quad * 8;

    for (int c = 0; c < 4; ++c) {
        const int k0 = wave * 256 + c * 64;
        const bool needA = (k0 <= q0 + 15);
        const bool needB = (k0 + 63 >= q0 + 1);
        if (needA) {
            const int jA0 = k0 - q0 + SS - 16;
#pragma unroll
            for (int t = 0; t < 5; ++t) {
                int j = jA0 + t * 16 + ln;
                bf16x8 bp;
                if ((unsigned)j < (unsigned)SS) {
                    const float* prow = pbase + (size_t)j * DD;
#pragma unroll
                    for (int jj = 0; jj < 8; ++jj) bp[jj] = f2bf(prow[jj]);
                } else {
#pragma unroll
                    for (int jj = 0; jj < 8; ++jj) bp[jj] = (short)0;
                }
                f32x4 acc = {0.f, 0.f, 0.f, 0.f};
                acc = __builtin_amdgcn_mfma_f32_16x16x32_bf16(a_pA, bp, acc, 0, 0, 0);
#pragma unroll
                for (int r = 0; r < 4; ++r)
                    posbuf[wave][0][quad * 4 + r][t * 16 + ln] = acc[r];
            }
        }
        if (needB) {
            const int jB0 = k0 - q0 - 17;
#pragma unroll
            for (int t = 0; t < 5; ++t) {
                int j = jB0 + t * 16 + ln;
                bf16x8 bp;
                if ((unsigned)j < (unsigned)SS) {
                    const float* prow = pbase + (size_t)j * DD;
#pragma unroll
                    for (int jj = 0; jj < 8; ++jj) bp[jj] = f2bf(prow[jj]);
                } else {
#pragma unroll
                    for (int jj = 0; jj < 8; ++jj) bp[jj] = (short)0;
                }
                f32x4 acc = {0.f, 0.f, 0.f, 0.f};
                acc = __builtin_amdgcn_mfma_f32_16x16x32_bf16(a_pB, bp, acc, 0, 0, 0);
#pragma unroll
                for (int r = 0; r < 4; ++r)
                    posbuf[wave][1][quad * 4 + r][t * 16 + ln] = acc[r];
            }
        }
        // ensure this wave's LDS writes complete before the shifted reads
        asm volatile("s_waitcnt lgkmcnt(0)" ::: "memory");
#pragma unroll
        for (int t = 0; t < 4; ++t) {
            const int kk0 = k0 + t * 16;
            const float* krow = kp + ((size_t)(b * SS + kk0 + ln)) * DD + h * DH + quad * 8;
            bf16x8 bk;
#pragma unroll
            for (int jj = 0; jj < 8; ++jj) bk[jj] = f2bf(krow[jj]);
            f32x4 acc = {0.f, 0.f, 0.f, 0.f};
            acc = __builtin_amdgcn_mfma_f32_16x16x32_bf16(a_c, bk, acc, 0, 0, 0);
#pragma unroll
            for (int r = 0; r < 4; ++r) {
                const int qq = quad * 4 + r;
                const int kkl = t * 16 + ln;
                const int which = (k0 + kkl <= q0 + qq) ? 0 : 1;
                float pv = posbuf[wave][which][qq][kkl - qq + 15];
                ob[(size_t)qq * SS + k0 + kkl] = acc[r] + pv;
            }
        }
    }
}

// ---------------------------------------------------------------------------
// Softmax over each score row: scale, key-mask -> -1e9, exp-normalize.
// ---------------------------------------------------------------------------
__global__ __launch_bounds__(256) void softmax_kernel(
    float* __restrict__ attn, const int* __restrict__ mask) {
    const size_t row = blockIdx.x;          // (b*16+h)*1024 + q
    const int b = (int)(row >> 14);
    float* a = attn + (row << 10);
    const int* mrow = mask + ((size_t)b << 10);
    const int tid = threadIdx.x;
    const float scale = 0.04419417382415922f;   // 1/sqrt(512)
    float4 v = *(const float4*)(a + tid * 4);
    int4 mm = *(const int4*)(mrow + tid * 4);
    float s[4];
    s[0] = mm.x ? -1e9f : v.x * scale;
    s[1] = mm.y ? -1e9f : v.y * scale;
    s[2] = mm.z ? -1e9f : v.z * scale;
    s[3] = mm.w ? -1e9f : v.w * scale;
    float m = fmaxf(fmaxf(s[0], s[1]), fmaxf(s[2], s[3]));
#pragma unroll
    for (int off = 32; off >= 1; off >>= 1) m = fmaxf(m, __shfl_xor(m, off, 64));
    __shared__ float redm[4];
    __shared__ float redl[4];
    const int wid = tid >> 6, lane = tid & 63;
    if (lane == 0) redm[wid] = m;
    __syncthreads();
    m = fmaxf(fmaxf(redm[0], redm[1]), fmaxf(redm[2], redm[3]));
    float e[4];
    float l = 0.f;
#pragma unroll
    for (int jj = 0; jj < 4; ++jj) { e[jj] = __expf(s[jj] - m); l += e[jj]; }
#pragma unroll
    for (int off = 32; off >= 1; off >>= 1) l += __shfl_xor(l, off, 64);
    if (lane == 0) redl[wid] = l;
    __syncthreads();
    l = redl[0] + redl[1] + redl[2] + redl[3];
    const float inv = 1.f / l;
    float4 o;
    o.x = e[0] * inv; o.y = e[1] * inv; o.z = e[2] * inv; o.w = e[3] * inv;
    *(float4*)(a + tid * 4) = o;
}

// ---------------------------------------------------------------------------
// ctx[b,q,h,:] = attn[b,h,q,:] @ v[b,:,h,:]  via MFMA. attn read exactly once.
// Block (b,h,128 q). Wave handles 32 q x 32 d, k-chunks of 32.
// ---------------------------------------------------------------------------
__global__ __launch_bounds__(256) void ctx_mfma_kernel(
    const float* __restrict__ attn, const float* __restrict__ vp,
    float* __restrict__ ctx) {
    const int b = blockIdx.z, h = blockIdx.y, q0 = blockIdx.x * 128;
    const int tid = threadIdx.x, wave = tid >> 6, lane = tid & 63;
    const int ln = lane & 15, quad = lane >> 4;
    const int qw = q0 + wave * 32;
    const float* ab = attn + (((size_t)(b * HH + h)) << 20);
    f32x4 acc[2][2] = {};
    for (int k0 = 0; k0 < SS; k0 += 32) {
        bf16x8 afr[2], bfr[2];
#pragma unroll
        for (int mt = 0; mt < 2; ++mt) {
            const float* ar = ab + (size_t)(qw + mt * 16 + ln) * SS + k0 + quad * 8;
#pragma unroll
            for (int j = 0; j < 8; ++j) afr[mt][j] = f2bf(ar[j]);
        }
#pragma unroll
        for (int nt = 0; nt < 2; ++nt) {
            const float* vr = vp + ((size_t)(b * SS + k0 + quad * 8)) * DD + h * DH + nt * 16 + ln;
#pragma unroll
            for (int j = 0; j < 8; ++j) bfr[nt][j] = f2bf(vr[(size_t)j * DD]);
        }
#pragma unroll
        for (int mt = 0; mt < 2; ++mt)
#pragma unroll
            for (int nt = 0; nt < 2; ++nt)
                acc[mt][nt] = __builtin_amdgcn_mfma_f32_16x16x32_bf16(
                    afr[mt], bfr[nt], acc[mt][nt], 0, 0, 0);
    }
#pragma unroll
    for (int mt = 0; mt < 2; ++mt)
#pragma unroll
        for (int nt = 0; nt < 2; ++nt)
#pragma unroll
            for (int r = 0; r < 4; ++r)
                ctx[((size_t)(b * SS + qw + mt * 16 + quad * 4 + r)) * DD +
                    h * DH + nt * 16 + ln] = acc[mt][nt][r];
}

// ---------------------------------------------------------------------------
extern "C" void kernel_launch(void* const* d_in, const int* in_sizes, int n_in,
                              void* d_out, int out_size, void* d_ws, size_t ws_size,
                              hipStream_t stream) {
    const float* query = (const float*)d_in[0];
    const float* key   = (const float*)d_in[1];
    const float* value = (const float*)d_in[2];
    const unsigned char* mask_raw = (const unsigned char*)d_in[3];
    const float* enc   = (const float*)d_in[4];
    const float* Wq    = (const float*)d_in[5];
    const float* bq    = (const float*)d_in[6];
    const float* Wk    = (const float*)d_in[7];
    const float* Wv    = (const float*)d_in[8];
    const float* Wp    = (const float*)d_in[9];
    const float* u_b   = (const float*)d_in[10];
    const float* v_b   = (const float*)d_in[11];
    const float* Wo    = (const float*)d_in[12];
    const float* bo    = (const float*)d_in[13];

    float* ws   = (float*)d_ws;
    float* qprj = ws + OFF_Q;
    float* kprj = ws + OFF_K;
    float* vprj = ws + OFF_V;
    float* pprj = ws + OFF_P;
    float* ctx  = ws + OFF_CTX;
    int*   mnrm = (int*)(ws + OFF_MASK);

    float* outp = (float*)d_out;                 // (B,S,D)
    float* attn = outp + (size_t)BB * SS * DD;   // (B,H,S,S)

    mask_prep_kernel<<<1, 256, 0, stream>>>(mask_raw, mnrm);

    gemm_bias_kernel<<<dim3(64, 8), 256, 0, stream>>>(query, Wq, bq, qprj);
    gemm_bias_kernel<<<dim3(64, 8), 256, 0, stream>>>(key, Wk, nullptr, kprj);
    gemm_bias_kernel<<<dim3(64, 8), 256, 0, stream>>>(value, Wv, nullptr, vprj);
    gemm_bias_kernel<<<dim3(16, 8), 256, 0, stream>>>(enc, Wp, nullptr, pprj);

    score_kernel<<<dim3(SS / 16, HH, BB), 256, 0, stream>>>(
        qprj, kprj, pprj, u_b, v_b, attn);
    softmax_kernel<<<BB * HH * SS, 256, 0, stream>>>(attn, mnrm);
    ctx_mfma_kernel<<<dim3(SS / 128, HH, BB), 256, 0, stream>>>(attn, vprj, ctx);

    gemm_bias_kernel<<<dim3(64, 8), 256, 0, stream>>>(ctx, Wo, bo, outp);
}

// Round 3
// 589.317 us; speedup vs baseline: 1.6961x; 1.4053x over previous
//
#include <hip/hip_runtime.h>

#define BB 4
#define SS 1024
#define DD 512
#define HH 16
#define DH 32

typedef __attribute__((ext_vector_type(8))) short bf16x8;
typedef __attribute__((ext_vector_type(4))) float f32x4;

__device__ __forceinline__ short f2bf(float x) {
    union { float f; unsigned u; } v; v.f = x;
    unsigned r = (v.u + 0x7FFFu + ((v.u >> 16) & 1u)) >> 16;
    return (short)r;
}
__device__ __forceinline__ float bf2f(unsigned short u) {
    union { unsigned u; float f; } v; v.u = ((unsigned)u) << 16;
    return v.f;
}
__device__ __forceinline__ void gl_lds16(const void* g, void* l) {
    __builtin_amdgcn_global_load_lds(
        (const __attribute__((address_space(1))) unsigned int*)g,
        (__attribute__((address_space(3))) unsigned int*)l, 16, 0, 0);
}

// ---------------------------------------------------------------------------
// Mask normalization: detect byte-bool vs int32 layout, expand to int[4096].
// ---------------------------------------------------------------------------
__global__ void mask_prep_kernel(const unsigned char* __restrict__ raw,
                                 int* __restrict__ norm) {
    __shared__ int bad;
    if (threadIdx.x == 0) bad = 0;
    __syncthreads();
    const unsigned int* w = (const unsigned int*)raw;
    int isbad = 0;
    for (int i = threadIdx.x; i < 1024; i += 256)
        if (w[i] > 1u) isbad = 1;
    if (isbad) atomicOr(&bad, 1);
    __syncthreads();
    if (bad) {
        for (int i = threadIdx.x; i < BB * SS; i += 256)
            norm[i] = raw[i] != 0;
    } else {
        const int* wi = (const int*)raw;
        for (int i = threadIdx.x; i < BB * SS; i += 256)
            norm[i] = wi[i] != 0;
    }
}

// ---------------------------------------------------------------------------
// Elementwise fp32 -> bf16 convert (n4 = number of float4 groups)
// ---------------------------------------------------------------------------
__global__ __launch_bounds__(256) void conv_kernel(
    const float* __restrict__ x, unsigned short* __restrict__ y, int n4) {
    int i = blockIdx.x * 256 + threadIdx.x;
    if (i < n4) {
        float4 v = ((const float4*)x)[i];
        ushort4 o;
        o.x = (unsigned short)f2bf(v.x); o.y = (unsigned short)f2bf(v.y);
        o.z = (unsigned short)f2bf(v.z); o.w = (unsigned short)f2bf(v.w);
        ((ushort4*)y)[i] = o;
    }
}

// ---------------------------------------------------------------------------
// 512x512 transpose + convert: WT[n][k] = bf16(W[k][n])
// ---------------------------------------------------------------------------
__global__ __launch_bounds__(256) void tconv_kernel(
    const float* __restrict__ W, unsigned short* __restrict__ WT) {
    __shared__ float t[64][68];
    const int bx = blockIdx.x * 64, by = blockIdx.y * 64;
    const int tid = threadIdx.x;
    const int r = tid >> 4, c4 = (tid & 15) * 4;
#pragma unroll
    for (int i = 0; i < 4; ++i) {
        float4 v = *(const float4*)(W + (size_t)(bx + r + i * 16) * 512 + by + c4);
        t[r + i * 16][c4 + 0] = v.x; t[r + i * 16][c4 + 1] = v.y;
        t[r + i * 16][c4 + 2] = v.z; t[r + i * 16][c4 + 3] = v.w;
    }
    __syncthreads();
#pragma unroll
    for (int i = 0; i < 4; ++i) {
        int c = r + i * 16;
        ushort4 o;
        o.x = (unsigned short)f2bf(t[c4 + 0][c]);
        o.y = (unsigned short)f2bf(t[c4 + 1][c]);
        o.z = (unsigned short)f2bf(t[c4 + 2][c]);
        o.w = (unsigned short)f2bf(t[c4 + 3][c]);
        *(ushort4*)(WT + (size_t)(by + c) * 512 + bx + c4) = o;
    }
}

// ---------------------------------------------------------------------------
// bf16 MFMA GEMM: C[M x N] = A[M x 512] @ BT[N x 512]^T
// 128x128 tile, BK=64, global_load_lds staging with XOR slot swizzle
// (conflict-free ds_read_b128 fragments). MODE 0: fp32 out + bias;
// MODE 1: bf16 out row-major; MODE 2: bf16 out in vT[b][h][dh][s] layout.
// ---------------------------------------------------------------------------
template <int MODE>
__global__ __launch_bounds__(256) void gemm_mfma_kernel(
    const unsigned short* __restrict__ A, const unsigned short* __restrict__ BT,
    const float* __restrict__ bias, void* __restrict__ Cout, int N) {
    __shared__ unsigned short As[128 * 64];
    __shared__ unsigned short Bs[128 * 64];
    const int tid = threadIdx.x;
    const int w = tid >> 6, lane = tid & 63;
    const int wm = w >> 1, wn = w & 1;
    const int ln = lane & 15, quad = lane >> 4;
    const int m0 = blockIdx.x * 128, n0 = blockIdx.y * 128;
    f32x4 acc[4][4] = {};
    for (int k0 = 0; k0 < 512; k0 += 64) {
        __syncthreads();
#pragma unroll
        for (int i = 0; i < 4; ++i) {
            int slot = i * 256 + tid;
            int row = slot >> 3, sl = slot & 7;
            int gsl = sl ^ (row & 7);
            gl_lds16(A + (size_t)(m0 + row) * 512 + k0 + gsl * 8, As + slot * 8);
            gl_lds16(BT + (size_t)(n0 + row) * 512 + k0 + gsl * 8, Bs + slot * 8);
        }
        __syncthreads();
#pragma unroll
        for (int kc = 0; kc < 2; ++kc) {
            bf16x8 af[4], bfr[4];
#pragma unroll
            for (int mt = 0; mt < 4; ++mt) {
                int row = wm * 64 + mt * 16 + ln;
                int sl = (kc * 4 + quad) ^ (row & 7);
                af[mt] = *(const bf16x8*)(As + row * 64 + sl * 8);
            }
#pragma unroll
            for (int nt = 0; nt < 4; ++nt) {
                int row = wn * 64 + nt * 16 + ln;
                int sl = (kc * 4 + quad) ^ (row & 7);
                bfr[nt] = *(const bf16x8*)(Bs + row * 64 + sl * 8);
            }
#pragma unroll
            for (int mt = 0; mt < 4; ++mt)
#pragma unroll
                for (int nt = 0; nt < 4; ++nt)
                    acc[mt][nt] = __builtin_amdgcn_mfma_f32_16x16x32_bf16(
                        af[mt], bfr[nt], acc[mt][nt], 0, 0, 0);
        }
    }
#pragma unroll
    for (int mt = 0; mt < 4; ++mt) {
#pragma unroll
        for (int nt = 0; nt < 4; ++nt) {
            int col = n0 + wn * 64 + nt * 16 + ln;
#pragma unroll
            for (int r = 0; r < 4; ++r) {
                int row = m0 + wm * 64 + mt * 16 + quad * 4 + r;
                float v = acc[mt][nt][r];
                if (MODE == 0) {
                    ((float*)Cout)[(size_t)row * N + col] = v + bias[col];
                } else if (MODE == 1) {
                    ((unsigned short*)Cout)[(size_t)row * N + col] =
                        (unsigned short)f2bf(v);
                } else {
                    int hh = row >> 5, dh = row & 31;
                    int bb = col >> 10, si = col & 1023;
                    ((unsigned short*)Cout)[(((size_t)(bb * HH + hh) * 32 + dh) << 10) + si] =
                        (unsigned short)f2bf(v);
                }
            }
        }
    }
}

// ---------------------------------------------------------------------------
// Fused attention: per (b,h,16 q-rows):
//   phase 1: raw scores (content + rel-shifted pos) -> LDS (bf16)
//   phase 2: softmax (scale, mask, exp-normalize); write attn global once
//            (coalesced 256B/row); keep unnormalized e in LDS (bf16)
//   phase 3: ctx = e @ V via MFMA (V from vT layout), 1/l folded in epilogue
// ---------------------------------------------------------------------------
__global__ __launch_bounds__(256) void fused_attn_kernel(
    const float* __restrict__ qp, const unsigned short* __restrict__ kp,
    const unsigned short* __restrict__ pp, const unsigned short* __restrict__ vT,
    const float* __restrict__ ub, const float* __restrict__ vb,
    const int* __restrict__ mask, float* __restrict__ attn,
    float* __restrict__ ctx) {
    const int b = blockIdx.z, h = blockIdx.y, q0 = blockIdx.x * 16;
    const int tid = threadIdx.x;
    const int w = tid >> 6, lane = tid & 63;
    const int ln = lane & 15, quad = lane >> 4;

    __shared__ unsigned short sbf[16][1032];
    __shared__ union U {
        unsigned short pos[4][2][16][88];
        f32x4 red[4][2][64];
    } u;
    __shared__ float invLDS[16];

    // ---- phase 1: scores ----
    bf16x8 a_c, a_pA, a_pB;
    {
        const float* qrow = qp + ((size_t)(b * SS + q0 + ln)) * DD + h * DH + quad * 8;
        const int qrB = q0 + ln + 1;
        const float* qrowB = qp + ((size_t)(b * SS + qrB)) * DD + h * DH + quad * 8;
#pragma unroll
        for (int j = 0; j < 8; ++j) {
            float uu = ub[h * DH + quad * 8 + j];
            float vv = vb[h * DH + quad * 8 + j];
            float qv = qrow[j];
            a_c[j] = f2bf(qv + uu);
            a_pA[j] = f2bf(qv + vv);
            a_pB[j] = (qrB < SS) ? f2bf(qrowB[j] + vv) : (short)0;
        }
    }
    const unsigned short* pbase = pp + h * DH + quad * 8;
    const int kw = w * 256;
    for (int c = 0; c < 4; ++c) {
        const int k0 = kw + c * 64;
        const bool needA = (k0 <= q0 + 15);
        const bool needB = (k0 + 63 >= q0 + 1);
        if (needA) {
            const int jA0 = k0 - q0 + SS - 16;
#pragma unroll
            for (int t = 0; t < 5; ++t) {
                int j = jA0 + t * 16 + ln;
                bf16x8 bp;
                if ((unsigned)j < (unsigned)SS) {
                    bp = *(const bf16x8*)(pbase + (size_t)j * DD);
                } else {
#pragma unroll
                    for (int jj = 0; jj < 8; ++jj) bp[jj] = (short)0;
                }
                f32x4 acc = {0.f, 0.f, 0.f, 0.f};
                acc = __builtin_amdgcn_mfma_f32_16x16x32_bf16(a_pA, bp, acc, 0, 0, 0);
#pragma unroll
                for (int r = 0; r < 4; ++r)
                    u.pos[w][0][quad * 4 + r][t * 16 + ln] =
                        (unsigned short)f2bf(acc[r]);
            }
        }
        if (needB) {
            const int jB0 = k0 - q0 - 17;
#pragma unroll
            for (int t = 0; t < 5; ++t) {
                int j = jB0 + t * 16 + ln;
                bf16x8 bp;
                if ((unsigned)j < (unsigned)SS) {
                    bp = *(const bf16x8*)(pbase + (size_t)j * DD);
                } else {
#pragma unroll
                    for (int jj = 0; jj < 8; ++jj) bp[jj] = (short)0;
                }
                f32x4 acc = {0.f, 0.f, 0.f, 0.f};
                acc = __builtin_amdgcn_mfma_f32_16x16x32_bf16(a_pB, bp, acc, 0, 0, 0);
#pragma unroll
                for (int r = 0; r < 4; ++r)
                    u.pos[w][1][quad * 4 + r][t * 16 + ln] =
                        (unsigned short)f2bf(acc[r]);
            }
        }
        asm volatile("s_waitcnt lgkmcnt(0)" ::: "memory");
#pragma unroll
        for (int t = 0; t < 4; ++t) {
            const int kk0 = k0 + t * 16;
            bf16x8 bk = *(const bf16x8*)(
                kp + ((size_t)(b * SS + kk0 + ln)) * DD + h * DH + quad * 8);
            f32x4 acc = {0.f, 0.f, 0.f, 0.f};
            acc = __builtin_amdgcn_mfma_f32_16x16x32_bf16(a_c, bk, acc, 0, 0, 0);
#pragma unroll
            for (int r = 0; r < 4; ++r) {
                const int qq = quad * 4 + r;
                const int kkl = t * 16 + ln;
                const int which = (k0 + kkl <= q0 + qq) ? 0 : 1;
                float pv = bf2f(u.pos[w][which][qq][kkl - qq + 15]);
                sbf[qq][k0 + kkl] = (unsigned short)f2bf(acc[r] + pv);
            }
        }
    }
    __syncthreads();

    // ---- phase 2: softmax ----
    const int r2 = tid >> 4, ci = tid & 15;
    const float scale = 0.04419417382415922f;   // 1/sqrt(512)
    float ebuf[64];
    const int* mrow = mask + ((size_t)b << 10);
    float mx = -3.4e38f;
#pragma unroll
    for (int i = 0; i < 16; ++i) {
        int col = i * 64 + ci * 4;
        ushort4 sv = *(const ushort4*)&sbf[r2][col];
        int4 mm = *(const int4*)(mrow + col);
        float v0 = mm.x ? -1e9f : bf2f(sv.x) * scale;
        float v1 = mm.y ? -1e9f : bf2f(sv.y) * scale;
        float v2 = mm.z ? -1e9f : bf2f(sv.z) * scale;
        float v3 = mm.w ? -1e9f : bf2f(sv.w) * scale;
        ebuf[i * 4 + 0] = v0; ebuf[i * 4 + 1] = v1;
        ebuf[i * 4 + 2] = v2; ebuf[i * 4 + 3] = v3;
        mx = fmaxf(mx, fmaxf(fmaxf(v0, v1), fmaxf(v2, v3)));
    }
#pragma unroll
    for (int off = 1; off <= 8; off <<= 1) mx = fmaxf(mx, __shfl_xor(mx, off, 64));
    float l = 0.f;
#pragma unroll
    for (int i = 0; i < 64; ++i) {
        float e = __expf(ebuf[i] - mx);
        ebuf[i] = e; l += e;
    }
#pragma unroll
    for (int off = 1; off <= 8; off <<= 1) l += __shfl_xor(l, off, 64);
    const float inv = 1.f / l;
    float* arow = attn + (((size_t)(b * HH + h)) << 20) + (size_t)(q0 + r2) * SS;
#pragma unroll
    for (int i = 0; i < 16; ++i) {
        int col = i * 64 + ci * 4;
        ushort4 eo;
        eo.x = (unsigned short)f2bf(ebuf[i * 4 + 0]);
        eo.y = (unsigned short)f2bf(ebuf[i * 4 + 1]);
        eo.z = (unsigned short)f2bf(ebuf[i * 4 + 2]);
        eo.w = (unsigned short)f2bf(ebuf[i * 4 + 3]);
        *(ushort4*)&sbf[r2][col] = eo;
        float4 ao = make_float4(ebuf[i * 4 + 0] * inv, ebuf[i * 4 + 1] * inv,
                                ebuf[i * 4 + 2] * inv, ebuf[i * 4 + 3] * inv);
        *(float4*)&arow[col] = ao;
    }
    if (ci == 0) invLDS[r2] = inv;
    __syncthreads();

    // ---- phase 3: ctx = e @ V ----
    f32x4 cacc0 = {0.f, 0.f, 0.f, 0.f}, cacc1 = {0.f, 0.f, 0.f, 0.f};
    const size_t vbase = ((size_t)(b * HH + h)) << 15;   // *32*1024
#pragma unroll
    for (int cch = 0; cch < 8; ++cch) {
        int k0 = w * 256 + cch * 32;
        bf16x8 af = *(const bf16x8*)&sbf[ln][k0 + quad * 8];
        bf16x8 v0 = *(const bf16x8*)(vT + vbase + (((size_t)ln) << 10) + k0 + quad * 8);
        bf16x8 v1 = *(const bf16x8*)(vT + vbase + (((size_t)(16 + ln)) << 10) + k0 + quad * 8);
        cacc0 = __builtin_amdgcn_mfma_f32_16x16x32_bf16(af, v0, cacc0, 0, 0, 0);
        cacc1 = __builtin_amdgcn_mfma_f32_16x16x32_bf16(af, v1, cacc1, 0, 0, 0);
    }
    u.red[w][0][lane] = cacc0;
    u.red[w][1][lane] = cacc1;
    __syncthreads();
    if (tid < 128) {
        int nt = tid >> 6, l2 = tid & 63;
        f32x4 s4 = u.red[0][nt][l2] + u.red[1][nt][l2] +
                   u.red[2][nt][l2] + u.red[3][nt][l2];
        int qd = l2 >> 4, lc = l2 & 15;
#pragma unroll
        for (int r = 0; r < 4; ++r) {
            int qq = qd * 4 + r;
            ctx[((size_t)(b * SS + q0 + qq)) * DD + h * DH + nt * 16 + lc] =
                s4[r] * invLDS[qq];
        }
    }
}

// ---------------------------------------------------------------------------
// fp32 GEMM for the output projection (kept fp32 for accuracy headroom)
// ---------------------------------------------------------------------------
__global__ __launch_bounds__(256) void gemm_bias_kernel(
    const float* __restrict__ A, const float* __restrict__ W,
    const float* __restrict__ bias, float* __restrict__ C) {
    __shared__ float Asm[64][20];
    __shared__ float Wsm[16][72];
    const int tid = threadIdx.x;
    const int tx = tid & 15, ty = tid >> 4;
    const int m0 = blockIdx.x * 64, n0 = blockIdx.y * 64;
    const int lr = tid >> 2;
    const int lk4 = (tid & 3) * 4;
    const int wk = tid >> 4;
    const int wn4 = (tid & 15) * 4;
    float acc[4][4] = {};
    for (int k0 = 0; k0 < 512; k0 += 16) {
        __syncthreads();
        *(float4*)&Asm[lr][lk4] =
            *(const float4*)(A + (size_t)(m0 + lr) * 512 + k0 + lk4);
        *(float4*)&Wsm[wk][wn4] =
            *(const float4*)(W + (size_t)(k0 + wk) * 512 + n0 + wn4);
        __syncthreads();
#pragma unroll
        for (int kk4 = 0; kk4 < 16; kk4 += 4) {
            float4 w0 = *(const float4*)&Wsm[kk4 + 0][tx * 4];
            float4 w1 = *(const float4*)&Wsm[kk4 + 1][tx * 4];
            float4 w2 = *(const float4*)&Wsm[kk4 + 2][tx * 4];
            float4 w3 = *(const float4*)&Wsm[kk4 + 3][tx * 4];
#pragma unroll
            for (int i = 0; i < 4; ++i) {
                float4 a4 = *(const float4*)&Asm[ty * 4 + i][kk4];
                acc[i][0] += a4.x * w0.x + a4.y * w1.x + a4.z * w2.x + a4.w * w3.x;
                acc[i][1] += a4.x * w0.y + a4.y * w1.y + a4.z * w2.y + a4.w * w3.y;
                acc[i][2] += a4.x * w0.z + a4.y * w1.z + a4.z * w2.z + a4.w * w3.z;
                acc[i][3] += a4.x * w0.w + a4.y * w1.w + a4.z * w2.w + a4.w * w3.w;
            }
        }
    }
    float4 bv = *(const float4*)(bias + n0 + tx * 4);
#pragma unroll
    for (int i = 0; i < 4; ++i) {
        float4 o;
        o.x = acc[i][0] + bv.x; o.y = acc[i][1] + bv.y;
        o.z = acc[i][2] + bv.z; o.w = acc[i][3] + bv.w;
        *(float4*)(C + (size_t)(m0 + ty * 4 + i) * 512 + n0 + tx * 4) = o;
    }
}

// ---------------------------------------------------------------------------
extern "C" void kernel_launch(void* const* d_in, const int* in_sizes, int n_in,
                              void* d_out, int out_size, void* d_ws, size_t ws_size,
                              hipStream_t stream) {
    const float* query = (const float*)d_in[0];
    const float* key   = (const float*)d_in[1];
    const float* value = (const float*)d_in[2];
    const unsigned char* mask_raw = (const unsigned char*)d_in[3];
    const float* enc   = (const float*)d_in[4];
    const float* Wq    = (const float*)d_in[5];
    const float* bq    = (const float*)d_in[6];
    const float* Wk    = (const float*)d_in[7];
    const float* Wv    = (const float*)d_in[8];
    const float* Wp    = (const float*)d_in[9];
    const float* u_b   = (const float*)d_in[10];
    const float* v_b   = (const float*)d_in[11];
    const float* Wo    = (const float*)d_in[12];
    const float* bo    = (const float*)d_in[13];

    char* wsb = (char*)d_ws;
    float*          qprj = (float*)(wsb + 0);                     // 8 MB fp32
    unsigned short* kprj = (unsigned short*)(wsb + 8388608);      // 4 MB bf16
    unsigned short* vT   = (unsigned short*)(wsb + 12582912);     // 4 MB bf16
    unsigned short* pprj = (unsigned short*)(wsb + 16777216);     // 1 MB bf16
    int*            mnrm = (int*)(wsb + 17825792);                // 16 KB
    float*          ctx  = (float*)(wsb + 17842176);              // 8 MB fp32
    // transients alias the ctx region (dead before fused_attn writes ctx)
    unsigned short* qbf  = (unsigned short*)(wsb + 17842176);
    unsigned short* kbf  = (unsigned short*)(wsb + 22036480);
    unsigned short* vbf  = (unsigned short*)(wsb + 26230784);
    unsigned short* ebf  = (unsigned short*)(wsb + 30425088);
    unsigned short* WqT  = (unsigned short*)(wsb + 31473664);
    unsigned short* WkT  = (unsigned short*)(wsb + 31997952);
    unsigned short* WvT  = (unsigned short*)(wsb + 32522240);
    unsigned short* WpT  = (unsigned short*)(wsb + 33046528);

    float* outp = (float*)d_out;                 // (B,S,D)
    float* attn = outp + (size_t)BB * SS * DD;   // (B,H,S,S)

    mask_prep_kernel<<<1, 256, 0, stream>>>(mask_raw, mnrm);

    conv_kernel<<<2048, 256, 0, stream>>>(query, qbf, 524288);
    conv_kernel<<<2048, 256, 0, stream>>>(key, kbf, 524288);
    conv_kernel<<<2048, 256, 0, stream>>>(value, vbf, 524288);
    conv_kernel<<<512, 256, 0, stream>>>(enc, ebf, 131072);

    tconv_kernel<<<dim3(8, 8), 256, 0, stream>>>(Wq, WqT);
    tconv_kernel<<<dim3(8, 8), 256, 0, stream>>>(Wk, WkT);
    tconv_kernel<<<dim3(8, 8), 256, 0, stream>>>(Wv, WvT);
    tconv_kernel<<<dim3(8, 8), 256, 0, stream>>>(Wp, WpT);

    gemm_mfma_kernel<0><<<dim3(32, 4), 256, 0, stream>>>(qbf, WqT, bq, qprj, 512);
    gemm_mfma_kernel<1><<<dim3(32, 4), 256, 0, stream>>>(kbf, WkT, nullptr, kprj, 512);
    gemm_mfma_kernel<2><<<dim3(4, 32), 256, 0, stream>>>(WvT, vbf, nullptr, vT, 4096);
    gemm_mfma_kernel<1><<<dim3(8, 4), 256, 0, stream>>>(ebf, WpT, nullptr, pprj, 512);

    fused_attn_kernel<<<dim3(SS / 16, HH, BB), 256, 0, stream>>>(
        qprj, kprj, pprj, vT, u_b, v_b, mnrm, attn, ctx);

    gemm_bias_kernel<<<dim3(64, 8), 256, 0, stream>>>(ctx, Wo, bo, outp);
}